// Round 2
// baseline (1152.052 us; speedup 1.0000x reference)
//
#include <hip/hip_runtime.h>

// ---------------- constants ----------------
#define N_NODES 65536
#define D_MODEL 256
#define DFF     1024
#define E1_N    1048576
#define E2_N    524288
#define ATT_SCALE 0.17677669529663687f   // 1/sqrt(32)
#define LN_EPS  1e-5f

typedef __attribute__((ext_vector_type(8))) __bf16 bf16x8;
typedef __attribute__((ext_vector_type(4))) float  floatx4;
typedef __attribute__((ext_vector_type(4))) unsigned short ushortx4;

__device__ __forceinline__ float bf2f(unsigned short u) {
  return __uint_as_float(((unsigned)u) << 16);
}
__device__ __forceinline__ unsigned short f2bf(float f) {
  unsigned u = __float_as_uint(f);
  return (unsigned short)((u + 0x7FFFu + ((u >> 16) & 1u)) >> 16);
}

// ---------------- prep kernels ----------------
// W [K][Nc] fp32 row-major -> Wt [Nc][K] bf16 row-major
__global__ __launch_bounds__(256) void transpose_w(const float* __restrict__ W,
                                                   unsigned short* __restrict__ Wt,
                                                   int K, int Nc) {
  int idx = blockIdx.x * 256 + threadIdx.x;
  if (idx < K * Nc) {
    int n = idx / K, kk = idx - n * K;
    Wt[idx] = f2bf(W[(size_t)kk * Nc + n]);
  }
}

__global__ __launch_bounds__(256) void f2bf_kernel(const float* __restrict__ in,
                                                   unsigned short* __restrict__ out, int n4) {
  int i = blockIdx.x * 256 + threadIdx.x;
  if (i < n4) {
    float4 v = ((const float4*)in)[i];
    ushortx4 o;
    o.x = f2bf(v.x); o.y = f2bf(v.y); o.z = f2bf(v.z); o.w = f2bf(v.w);
    ((ushortx4*)out)[i] = o;
  }
}

__global__ __launch_bounds__(256) void zero_kernel(int* __restrict__ p, int n) {
  int i = blockIdx.x * 256 + threadIdx.x;
  if (i < n) p[i] = 0;
}

// ---------------- CSR build ----------------
__global__ __launch_bounds__(256) void hist_kernel(const int* __restrict__ dst,
                                                   int* __restrict__ cnt, int E) {
  int e = blockIdx.x * 256 + threadIdx.x;
  if (e < E) atomicAdd(&cnt[dst[e]], 1);
}

// single block, 1024 threads, 64 elems/thread over 65536 counts
__global__ __launch_bounds__(1024) void scan_kernel(const int* __restrict__ cnt,
                                                    int* __restrict__ row_start,
                                                    int* __restrict__ cur, int total) {
  __shared__ int lds[1024];
  const int tid = threadIdx.x;
  const int base = tid * 64;
  int s = 0;
  for (int i = 0; i < 64; ++i) s += cnt[base + i];
  lds[tid] = s;
  __syncthreads();
  int v = s;
  for (int off = 1; off < 1024; off <<= 1) {
    int add = (tid >= off) ? lds[tid - off] : 0;
    __syncthreads();
    v += add;
    lds[tid] = v;
    __syncthreads();
  }
  int run = v - s;  // exclusive prefix of this chunk
  for (int i = 0; i < 64; ++i) {
    int c = cnt[base + i];
    row_start[base + i] = run;
    cur[base + i] = run;
    run += c;
  }
  if (tid == 1023) row_start[N_NODES] = total;
}

__global__ __launch_bounds__(256) void scatter_kernel(const int* __restrict__ src,
                                                      const int* __restrict__ dst,
                                                      const int* __restrict__ et,
                                                      int* __restrict__ cur,
                                                      int* __restrict__ s_src,
                                                      int* __restrict__ s_et, int E) {
  int e = blockIdx.x * 256 + threadIdx.x;
  if (e < E) {
    int p = atomicAdd(&cur[dst[e]], 1);
    s_src[p] = src[e];
    if (s_et) s_et[p] = et[e];
  }
}

// ---------------- GEMM: C[M][N] = A[M][K] @ Bt[N][K]^T, bf16 in, bf16 out ----------------
// 128x128 tile / block of 256 threads (4 waves, 2x2 of 64x64), BK=32.
// Staging via plain 16B vector loads + LDS stores (conservative; no global_load_lds).
template <bool BIAS, bool RELU>
__global__ __launch_bounds__(256) void gemm_bf16(const unsigned short* __restrict__ A,
                                                 const unsigned short* __restrict__ Bt,
                                                 const float* __restrict__ bias,
                                                 unsigned short* __restrict__ C,
                                                 int K, int Ntot) {
  __shared__ __align__(16) unsigned short sA[128 * 32];
  __shared__ __align__(16) unsigned short sB[128 * 32];
  const int tid  = threadIdx.x;
  const int wave = tid >> 6;
  const int lane = tid & 63;
  const int m0 = blockIdx.x * 128;
  const int n0 = blockIdx.y * 128;

  floatx4 acc[4][4] = {};

  const int fr = lane & 15;         // m/n within 16x16 tile
  const int fk = (lane >> 4) * 8;   // k offset of this lane-quad
  const int wy = (wave >> 1) * 64;  // wave's m offset
  const int wx = (wave & 1) * 64;   // wave's n offset

  for (int k0 = 0; k0 < K; k0 += 32) {
#pragma unroll
    for (int t = 0; t < 2; ++t) {
      const int g  = tid + t * 256;   // 16B-granule id, 0..511
      const int r  = g >> 2;          // tile row 0..127
      const int c8 = (g & 3) * 8;     // bf16 col offset within BK=32
      *(bf16x8*)&sA[r * 32 + c8] = *(const bf16x8*)(A  + (size_t)(m0 + r) * K + k0 + c8);
      *(bf16x8*)&sB[r * 32 + c8] = *(const bf16x8*)(Bt + (size_t)(n0 + r) * K + k0 + c8);
    }
    __syncthreads();
    bf16x8 af[4], bfv[4];
#pragma unroll
    for (int i = 0; i < 4; ++i) af[i]  = *(const bf16x8*)&sA[(wy + i * 16 + fr) * 32 + fk];
#pragma unroll
    for (int j = 0; j < 4; ++j) bfv[j] = *(const bf16x8*)&sB[(wx + j * 16 + fr) * 32 + fk];
#pragma unroll
    for (int i = 0; i < 4; ++i)
#pragma unroll
      for (int j = 0; j < 4; ++j)
        acc[i][j] = __builtin_amdgcn_mfma_f32_16x16x32_bf16(af[i], bfv[j], acc[i][j], 0, 0, 0);
    __syncthreads();
  }

  // epilogue: D col(n) = lane&15, row(m) = (lane>>4)*4 + r
  const int coln = lane & 15;
  const int rowq = (lane >> 4) * 4;
#pragma unroll
  for (int j = 0; j < 4; ++j) {
    const int n = n0 + wx + j * 16 + coln;
    float bval = 0.f;
    if (BIAS) bval = bias[n];
#pragma unroll
    for (int i = 0; i < 4; ++i) {
      const int mbase = m0 + wy + i * 16 + rowq;
#pragma unroll
      for (int r = 0; r < 4; ++r) {
        float v = acc[i][j][r] + bval;
        if (RELU) v = fmaxf(v, 0.f);
        C[(size_t)(mbase + r) * Ntot + n] = f2bf(v);
      }
    }
  }
}

// ---------------- fused per-dst graph attention ----------------
// one wave per dst node; lane = head(3b) x slot(3b); slot covers 4 dims of 32
template <bool HAS_REL>
__global__ __launch_bounds__(256) void attn_kernel(const unsigned short* __restrict__ qb, int qstride,
                                                   const unsigned short* __restrict__ kb,
                                                   const unsigned short* __restrict__ vb, int kvstride,
                                                   const int* __restrict__ row_start,
                                                   const int* __restrict__ s_src,
                                                   const int* __restrict__ s_et,
                                                   const float* __restrict__ ak_embed,
                                                   unsigned short* __restrict__ outp) {
  const int lane = threadIdx.x & 63;
  const int wave = threadIdx.x >> 6;
  const int dst  = blockIdx.x * 4 + wave;
  const int s    = lane & 7;
  const int doff = (lane >> 3) * 32 + s * 4;

  ushortx4 qu = *(const ushortx4*)(qb + (size_t)dst * qstride + doff);
  const float q0 = bf2f(qu.x), q1 = bf2f(qu.y), q2 = bf2f(qu.z), q3 = bf2f(qu.w);

  float a0 = 0.f, a1 = 0.f, a2 = 0.f, a3 = 0.f, lsum = 0.f;
  const int beg = row_start[dst], end = row_start[dst + 1];
  for (int j = beg; j < end; ++j) {
    const int src = s_src[j];
    ushortx4 ku = *(const ushortx4*)(kb + (size_t)src * kvstride + doff);
    float part = bf2f(ku.x) * q0 + bf2f(ku.y) * q1 + bf2f(ku.z) * q2 + bf2f(ku.w) * q3;
    if (HAS_REL) {
      const int et = s_et[j];
      float4 akv = *(const float4*)(ak_embed + (size_t)et * 32 + s * 4);
      part += akv.x * q0 + akv.y * q1 + akv.z * q2 + akv.w * q3;
    }
    part += __shfl_xor(part, 1);
    part += __shfl_xor(part, 2);
    part += __shfl_xor(part, 4);
    // e*SCALE ~ N(0,1): exp-safe without segment-max (softmax shift-invariant)
    const float pw = __expf(part * ATT_SCALE);
    lsum += pw;
    ushortx4 vu = *(const ushortx4*)(vb + (size_t)src * kvstride + doff);
    a0 += pw * bf2f(vu.x); a1 += pw * bf2f(vu.y);
    a2 += pw * bf2f(vu.z); a3 += pw * bf2f(vu.w);
  }
  const float inv = lsum > 0.f ? 1.f / lsum : 0.f;
  ushortx4 o;
  o.x = f2bf(a0 * inv); o.y = f2bf(a1 * inv); o.z = f2bf(a2 * inv); o.w = f2bf(a3 * inv);
  *(ushortx4*)(outp + (size_t)dst * 256 + doff) = o;
}

// ---------------- residual + LayerNorm (wave per row, in-place safe) ----------------
template <bool WRITE_BF>
__global__ __launch_bounds__(256) void ln_kernel(const float* __restrict__ xin,
                                                 const unsigned short* __restrict__ oin,
                                                 const float* __restrict__ g,
                                                 const float* __restrict__ b,
                                                 float* __restrict__ xout,
                                                 unsigned short* __restrict__ bfout) {
  const int lane = threadIdx.x & 63;
  const int wave = threadIdx.x >> 6;
  const size_t row  = (size_t)blockIdx.x * 4 + wave;
  const size_t base = row * 256 + lane * 4;
  float4 xv = *(const float4*)(xin + base);
  ushortx4 ou = *(const ushortx4*)(oin + base);
  const float x0 = xv.x + bf2f(ou.x), x1 = xv.y + bf2f(ou.y),
              x2 = xv.z + bf2f(ou.z), x3 = xv.w + bf2f(ou.w);
  float sum = x0 + x1 + x2 + x3;
  float ss  = x0 * x0 + x1 * x1 + x2 * x2 + x3 * x3;
#pragma unroll
  for (int m = 1; m <= 32; m <<= 1) {
    sum += __shfl_xor(sum, m);
    ss  += __shfl_xor(ss, m);
  }
  const float mu  = sum * (1.f / 256.f);
  const float var = ss * (1.f / 256.f) - mu * mu;
  const float rs  = rsqrtf(var + LN_EPS);
  float4 gv = *(const float4*)(g + lane * 4);
  float4 bv = *(const float4*)(b + lane * 4);
  const float y0 = (x0 - mu) * rs * gv.x + bv.x;
  const float y1 = (x1 - mu) * rs * gv.y + bv.y;
  const float y2 = (x2 - mu) * rs * gv.z + bv.z;
  const float y3 = (x3 - mu) * rs * gv.w + bv.w;
  *(float4*)(xout + base) = make_float4(y0, y1, y2, y3);
  if (WRITE_BF) {
    ushortx4 yo;
    yo.x = f2bf(y0); yo.y = f2bf(y1); yo.z = f2bf(y2); yo.w = f2bf(y3);
    *(ushortx4*)(bfout + base) = yo;
  }
}

// ---------------- launch ----------------
extern "C" void kernel_launch(void* const* d_in, const int* in_sizes, int n_in,
                              void* d_out, int out_size, void* d_ws, size_t ws_size,
                              hipStream_t stream) {
  const float* h_in      = (const float*)d_in[0];
  const float* mem_in    = (const float*)d_in[1];
  const int*   src_intra = (const int*)d_in[2];
  const int*   dst_intra = (const int*)d_in[3];
  const int*   etype     = (const int*)d_in[4];
  const int*   src_inter = (const int*)d_in[5];
  const int*   dst_inter = (const int*)d_in[6];
  const float* Wq0 = (const float*)d_in[7];
  const float* Wk0 = (const float*)d_in[8];
  const float* Wv0 = (const float*)d_in[9];
  const float* Wo0 = (const float*)d_in[10];
  const float* Wq1 = (const float*)d_in[11];
  const float* Wk1 = (const float*)d_in[12];
  const float* Wv1 = (const float*)d_in[13];
  const float* Wo1 = (const float*)d_in[14];
  const float* akE = (const float*)d_in[15];
  const float* ln0_g = (const float*)d_in[16];
  const float* ln0_b = (const float*)d_in[17];
  const float* ln1_g = (const float*)d_in[18];
  const float* ln1_b = (const float*)d_in[19];
  const float* ln2_g = (const float*)d_in[20];
  const float* ln2_b = (const float*)d_in[21];
  const float* Wf1 = (const float*)d_in[22];
  const float* bf1 = (const float*)d_in[23];
  const float* Wf2 = (const float*)d_in[24];
  const float* bf2 = (const float*)d_in[25];

  char* p = (char*)d_ws;
  auto alloc = [&](size_t bytes) {
    char* r = p;
    p += (bytes + 255) & ~(size_t)255;
    return r;
  };

  unsigned short* wqkv0t = (unsigned short*)alloc((size_t)768 * 256 * 2);
  unsigned short* wo0t   = (unsigned short*)alloc((size_t)256 * 256 * 2);
  unsigned short* wq1t   = (unsigned short*)alloc((size_t)256 * 256 * 2);
  unsigned short* wkv1t  = (unsigned short*)alloc((size_t)512 * 256 * 2);
  unsigned short* wo1t   = (unsigned short*)alloc((size_t)256 * 256 * 2);
  unsigned short* wf1t   = (unsigned short*)alloc((size_t)1024 * 256 * 2);
  unsigned short* wf2t   = (unsigned short*)alloc((size_t)256 * 1024 * 2);

  int* cnt0  = (int*)alloc((size_t)N_NODES * 4);
  int* rs0   = (int*)alloc((size_t)(N_NODES + 1) * 4);
  int* cur0  = (int*)alloc((size_t)N_NODES * 4);
  int* cnt1  = (int*)alloc((size_t)N_NODES * 4);
  int* rs1   = (int*)alloc((size_t)(N_NODES + 1) * 4);
  int* cur1  = (int*)alloc((size_t)N_NODES * 4);
  int* ssrc0 = (int*)alloc((size_t)E1_N * 4);
  int* set0  = (int*)alloc((size_t)E1_N * 4);
  int* ssrc1 = (int*)alloc((size_t)E2_N * 4);

  // buf1 [N,1024] capacity:
  //   phase1: qkv0 [N,768] + O0-out in tail [N,256]
  //   phase2: q1 [N,256] + kv1 [N,512] + O1-out in tail [N,256]
  //   phase3: ffn hidden [N,1024]
  unsigned short* buf1 = (unsigned short*)alloc((size_t)N_NODES * 1024 * 2);
  unsigned short* tail = buf1 + (size_t)N_NODES * 768;
  // buf2: h_bf -> attn0_out -> h1_bf -> attn1_out -> ffn2 out
  unsigned short* buf2 = (unsigned short*)alloc((size_t)N_NODES * 256 * 2);
  // buf3: mem_bf -> h2_bf
  unsigned short* buf3 = (unsigned short*)alloc((size_t)N_NODES * 256 * 2);

  float* hcur = (float*)d_out;  // fp32 residual chain lives in d_out

  const int TB = 256;
  const int g64k  = 256;   // 65536/256
  const int g256k = 1024;  // 262144/256

  // ---- phase 0: weights, casts, CSR ----
  transpose_w<<<g64k, TB, 0, stream>>>(Wq0, wqkv0t, 256, 256);
  transpose_w<<<g64k, TB, 0, stream>>>(Wk0, wqkv0t + 65536, 256, 256);
  transpose_w<<<g64k, TB, 0, stream>>>(Wv0, wqkv0t + 131072, 256, 256);
  transpose_w<<<g64k, TB, 0, stream>>>(Wo0, wo0t, 256, 256);
  transpose_w<<<g64k, TB, 0, stream>>>(Wq1, wq1t, 256, 256);
  transpose_w<<<g64k, TB, 0, stream>>>(Wk1, wkv1t, 256, 256);
  transpose_w<<<g64k, TB, 0, stream>>>(Wv1, wkv1t + 65536, 256, 256);
  transpose_w<<<g64k, TB, 0, stream>>>(Wo1, wo1t, 256, 256);
  transpose_w<<<g256k, TB, 0, stream>>>(Wf1, wf1t, 256, 1024);
  transpose_w<<<g256k, TB, 0, stream>>>(Wf2, wf2t, 1024, 256);

  f2bf_kernel<<<16384, TB, 0, stream>>>(h_in, buf2, N_NODES * 256 / 4);
  f2bf_kernel<<<16384, TB, 0, stream>>>(mem_in, buf3, N_NODES * 256 / 4);

  zero_kernel<<<g64k, TB, 0, stream>>>(cnt0, N_NODES);
  zero_kernel<<<g64k, TB, 0, stream>>>(cnt1, N_NODES);
  hist_kernel<<<E1_N / 256, TB, 0, stream>>>(dst_intra, cnt0, E1_N);
  hist_kernel<<<E2_N / 256, TB, 0, stream>>>(dst_inter, cnt1, E2_N);
  scan_kernel<<<1, 1024, 0, stream>>>(cnt0, rs0, cur0, E1_N);
  scan_kernel<<<1, 1024, 0, stream>>>(cnt1, rs1, cur1, E2_N);
  scatter_kernel<<<E1_N / 256, TB, 0, stream>>>(src_intra, dst_intra, etype, cur0, ssrc0, set0, E1_N);
  scatter_kernel<<<E2_N / 256, TB, 0, stream>>>(src_inter, dst_inter, nullptr, cur1, ssrc1, nullptr, E2_N);

  // ---- phase 1: intra attention ----
  gemm_bf16<false, false><<<dim3(512, 6), TB, 0, stream>>>(buf2, wqkv0t, nullptr, buf1, 256, 768);
  attn_kernel<true><<<16384, TB, 0, stream>>>(buf1, 768, buf1 + 256, buf1 + 512, 768,
                                              rs0, ssrc0, set0, akE, buf2);
  gemm_bf16<false, false><<<dim3(512, 2), TB, 0, stream>>>(buf2, wo0t, nullptr, tail, 256, 256);
  ln_kernel<true><<<16384, TB, 0, stream>>>(h_in, tail, ln0_g, ln0_b, hcur, buf2);

  // ---- phase 2: inter attention ----
  gemm_bf16<false, false><<<dim3(512, 2), TB, 0, stream>>>(buf2, wq1t, nullptr, buf1, 256, 256);
  unsigned short* kv1 = buf1 + (size_t)N_NODES * 256;
  gemm_bf16<false, false><<<dim3(512, 4), TB, 0, stream>>>(buf3, wkv1t, nullptr, kv1, 256, 512);
  attn_kernel<false><<<16384, TB, 0, stream>>>(buf1, 256, kv1, kv1 + 256, 512,
                                               rs1, ssrc1, nullptr, nullptr, buf2);
  gemm_bf16<false, false><<<dim3(512, 2), TB, 0, stream>>>(buf2, wo1t, nullptr, tail, 256, 256);
  ln_kernel<true><<<16384, TB, 0, stream>>>(hcur, tail, ln1_g, ln1_b, hcur, buf3);

  // ---- phase 3: FFN ----
  gemm_bf16<true, true><<<dim3(512, 8), TB, 0, stream>>>(buf3, wf1t, bf1, buf1, 256, 1024);
  gemm_bf16<true, false><<<dim3(512, 2), TB, 0, stream>>>(buf1, wf2t, bf2, buf2, 1024, 256);
  ln_kernel<false><<<16384, TB, 0, stream>>>(hcur, buf2, ln2_g, ln2_b, hcur, nullptr);
}

// Round 3
// 1122.979 us; speedup vs baseline: 1.0259x; 1.0259x over previous
//
#include <hip/hip_runtime.h>

// ---------------- constants ----------------
#define N_NODES 65536
#define D_MODEL 256
#define DFF     1024
#define E1_N    1048576
#define E2_N    524288
#define ATT_SCALE 0.17677669529663687f   // 1/sqrt(32)
#define LN_EPS  1e-5f

typedef __attribute__((ext_vector_type(8))) __bf16 bf16x8;
typedef __attribute__((ext_vector_type(4))) float  floatx4;
typedef __attribute__((ext_vector_type(4))) unsigned short ushortx4;
typedef __attribute__((ext_vector_type(8))) unsigned short ushortx8;

__device__ __forceinline__ float bf2f(unsigned short u) {
  return __uint_as_float(((unsigned)u) << 16);
}
__device__ __forceinline__ unsigned short f2bf(float f) {
  unsigned u = __float_as_uint(f);
  return (unsigned short)((u + 0x7FFFu + ((u >> 16) & 1u)) >> 16);
}

// async global->LDS, 16B per lane; LDS dst is wave-uniform base (+lane*16 by HW)
__device__ __forceinline__ void gld_lds16(const void* g, void* l) {
  __builtin_amdgcn_global_load_lds(
      (const __attribute__((address_space(1))) unsigned int*)g,
      (__attribute__((address_space(3))) unsigned int*)l, 16, 0, 0);
}

// ---------------- prep kernels ----------------
// W [K][Nc] fp32 row-major -> Wt [Nc][K] bf16 row-major, LDS-tiled 32x32
__global__ __launch_bounds__(256) void transpose_w(const float* __restrict__ W,
                                                   unsigned short* __restrict__ Wt,
                                                   int K, int Nc) {
  __shared__ float tile[32][33];
  const int tx = threadIdx.x & 31;
  const int ty = threadIdx.x >> 5;  // 0..7
  const int r0 = blockIdx.y * 32;
  const int c0 = blockIdx.x * 32;
#pragma unroll
  for (int p = 0; p < 4; ++p) {
    const int r = ty + p * 8;
    tile[r][tx] = W[(size_t)(r0 + r) * Nc + c0 + tx];
  }
  __syncthreads();
#pragma unroll
  for (int p = 0; p < 4; ++p) {
    const int r = ty + p * 8;  // row within Wt tile == col of W
    Wt[(size_t)(c0 + r) * K + r0 + tx] = f2bf(tile[tx][r]);
  }
}

__global__ __launch_bounds__(256) void f2bf_kernel(const float* __restrict__ in,
                                                   unsigned short* __restrict__ out, int n4) {
  int i = blockIdx.x * 256 + threadIdx.x;
  if (i < n4) {
    float4 v = ((const float4*)in)[i];
    ushortx4 o;
    o.x = f2bf(v.x); o.y = f2bf(v.y); o.z = f2bf(v.z); o.w = f2bf(v.w);
    ((ushortx4*)out)[i] = o;
  }
}

__global__ __launch_bounds__(256) void zero_kernel(int* __restrict__ p, int n) {
  int i = blockIdx.x * 256 + threadIdx.x;
  if (i < n) p[i] = 0;
}

// ---------------- CSR build ----------------
__global__ __launch_bounds__(256) void hist_kernel(const int* __restrict__ dst,
                                                   int* __restrict__ cnt, int E) {
  int e = blockIdx.x * 256 + threadIdx.x;
  if (e < E) atomicAdd(&cnt[dst[e]], 1);
}

// single block, 1024 threads, 64 elems/thread over 65536 counts
__global__ __launch_bounds__(1024) void scan_kernel(const int* __restrict__ cnt,
                                                    int* __restrict__ row_start,
                                                    int* __restrict__ cur, int total) {
  __shared__ int lds[1024];
  const int tid = threadIdx.x;
  const int base = tid * 64;
  int s = 0;
  for (int i = 0; i < 64; ++i) s += cnt[base + i];
  lds[tid] = s;
  __syncthreads();
  int v = s;
  for (int off = 1; off < 1024; off <<= 1) {
    int add = (tid >= off) ? lds[tid - off] : 0;
    __syncthreads();
    v += add;
    lds[tid] = v;
    __syncthreads();
  }
  int run = v - s;  // exclusive prefix of this chunk
  for (int i = 0; i < 64; ++i) {
    int c = cnt[base + i];
    row_start[base + i] = run;
    cur[base + i] = run;
    run += c;
  }
  if (tid == 1023) row_start[N_NODES] = total;
}

__global__ __launch_bounds__(256) void scatter_kernel(const int* __restrict__ src,
                                                      const int* __restrict__ dst,
                                                      const int* __restrict__ et,
                                                      int* __restrict__ cur,
                                                      int* __restrict__ s_src,
                                                      int* __restrict__ s_et, int E) {
  int e = blockIdx.x * 256 + threadIdx.x;
  if (e < E) {
    int p = atomicAdd(&cur[dst[e]], 1);
    s_src[p] = src[e];
    if (s_et) s_et[p] = et[e];
  }
}

// ---------------- GEMM: C[M][N] = A[M][K] @ Bt[N][K]^T, bf16 in, bf16 out ----------------
// 128x128 tile / block of 256 threads (4 waves, 2x2 of 64x64), BK=32,
// global_load_lds width-16 staging (m97 structure).
template <bool BIAS, bool RELU>
__global__ __launch_bounds__(256) void gemm_bf16(const unsigned short* __restrict__ A,
                                                 const unsigned short* __restrict__ Bt,
                                                 const float* __restrict__ bias,
                                                 unsigned short* __restrict__ C,
                                                 int K, int Ntot) {
  __shared__ __align__(16) unsigned short sA[128 * 32];
  __shared__ __align__(16) unsigned short sB[128 * 32];
  const int tid  = threadIdx.x;
  const int wave = tid >> 6;
  const int lane = tid & 63;
  const int m0 = blockIdx.x * 128;
  const int n0 = blockIdx.y * 128;

  floatx4 acc[4][4] = {};

  const int l4r = lane >> 2;        // 0..15: row within 16-row staging chunk
  const int l4c = (lane & 3) * 8;   // bf16 col offset within BK=32 (16B granule)
  const int fr = lane & 15;         // m/n within 16x16 tile
  const int fk = (lane >> 4) * 8;   // k offset of this lane-quad
  const int wy = (wave >> 1) * 64;  // wave's m offset
  const int wx = (wave & 1) * 64;   // wave's n offset

  for (int k0 = 0; k0 < K; k0 += 32) {
#pragma unroll
    for (int c = 0; c < 2; ++c) {
      const int row = wave * 32 + c * 16;
      gld_lds16(A  + ((size_t)(m0 + row + l4r) * K + k0 + l4c), &sA[row * 32]);
      gld_lds16(Bt + ((size_t)(n0 + row + l4r) * K + k0 + l4c), &sB[row * 32]);
    }
    __syncthreads();
    bf16x8 af[4], bfv[4];
#pragma unroll
    for (int i = 0; i < 4; ++i) af[i]  = *(const bf16x8*)&sA[(wy + i * 16 + fr) * 32 + fk];
#pragma unroll
    for (int j = 0; j < 4; ++j) bfv[j] = *(const bf16x8*)&sB[(wx + j * 16 + fr) * 32 + fk];
#pragma unroll
    for (int i = 0; i < 4; ++i)
#pragma unroll
      for (int j = 0; j < 4; ++j)
        acc[i][j] = __builtin_amdgcn_mfma_f32_16x16x32_bf16(af[i], bfv[j], acc[i][j], 0, 0, 0);
    __syncthreads();
  }

  // epilogue: D col(n) = lane&15, row(m) = (lane>>4)*4 + r
  const int coln = lane & 15;
  const int rowq = (lane >> 4) * 4;
#pragma unroll
  for (int j = 0; j < 4; ++j) {
    const int n = n0 + wx + j * 16 + coln;
    float bval = 0.f;
    if (BIAS) bval = bias[n];
#pragma unroll
    for (int i = 0; i < 4; ++i) {
      const int mbase = m0 + wy + i * 16 + rowq;
#pragma unroll
      for (int r = 0; r < 4; ++r) {
        float v = acc[i][j][r] + bval;
        if (RELU) v = fmaxf(v, 0.f);
        C[(size_t)(mbase + r) * Ntot + n] = f2bf(v);
      }
    }
  }
}

// ---------------- fused per-dst graph attention ----------------
// one wave per dst node, TWO edges in flight per iteration:
// lane = half(1b) x head(3b) x slot(2b); each lane covers 8 dims (16B loads)
template <bool HAS_REL>
__global__ __launch_bounds__(256) void attn_kernel(const unsigned short* __restrict__ qb, int qstride,
                                                   const unsigned short* __restrict__ kb,
                                                   const unsigned short* __restrict__ vb, int kvstride,
                                                   const int* __restrict__ row_start,
                                                   const int* __restrict__ s_src,
                                                   const int* __restrict__ s_et,
                                                   const float* __restrict__ ak_embed,
                                                   unsigned short* __restrict__ outp) {
  const int lane = threadIdx.x & 63;
  const int wave = threadIdx.x >> 6;
  const int dst  = blockIdx.x * 4 + wave;
  const int half = lane >> 5;   // which edge of the pair
  const int l    = lane & 31;   // head = l>>2, slot = l&3
  const int doff = l * 8;       // (l>>2)*32 + (l&3)*8 == l*8

  ushortx8 qu = *(const ushortx8*)(qb + (size_t)dst * qstride + doff);
  float q[8];
#pragma unroll
  for (int d = 0; d < 8; ++d) q[d] = bf2f(qu[d]);

  float a[8] = {0.f, 0.f, 0.f, 0.f, 0.f, 0.f, 0.f, 0.f};
  float lsum = 0.f;
  const int beg = row_start[dst], end = row_start[dst + 1];
  for (int j = beg; j < end; j += 2) {
    const int e = j + half;
    const bool valid = e < end;
    const int ecl = valid ? e : (end - 1);
    const int src = s_src[ecl];
    ushortx8 ku = *(const ushortx8*)(kb + (size_t)src * kvstride + doff);
    float part = 0.f;
#pragma unroll
    for (int d = 0; d < 8; ++d) part += bf2f(ku[d]) * q[d];
    if (HAS_REL) {
      const int et = s_et[ecl];
      const float* ak = ak_embed + (size_t)et * 32 + (l & 3) * 8;
      float4 ak0 = *(const float4*)ak;
      float4 ak1 = *(const float4*)(ak + 4);
      part += ak0.x * q[0] + ak0.y * q[1] + ak0.z * q[2] + ak0.w * q[3]
            + ak1.x * q[4] + ak1.y * q[5] + ak1.z * q[6] + ak1.w * q[7];
    }
    part += __shfl_xor(part, 1);
    part += __shfl_xor(part, 2);
    // e*SCALE ~ N(0,1): exp-safe without segment-max (softmax shift-invariant)
    const float pw = valid ? __expf(part * ATT_SCALE) : 0.f;
    lsum += pw;
    ushortx8 vu = *(const ushortx8*)(vb + (size_t)src * kvstride + doff);
#pragma unroll
    for (int d = 0; d < 8; ++d) a[d] += pw * bf2f(vu[d]);
  }
  // combine the two edge-halves
  lsum += __shfl_xor(lsum, 32);
#pragma unroll
  for (int d = 0; d < 8; ++d) a[d] += __shfl_xor(a[d], 32);
  const float inv = lsum > 0.f ? 1.f / lsum : 0.f;
  if (half == 0) {
    ushortx8 o;
#pragma unroll
    for (int d = 0; d < 8; ++d) o[d] = f2bf(a[d] * inv);
    *(ushortx8*)(outp + (size_t)dst * 256 + doff) = o;
  }
}

// ---------------- residual + LayerNorm (wave per row, in-place safe) ----------------
template <bool WRITE_BF>
__global__ __launch_bounds__(256) void ln_kernel(const float* __restrict__ xin,
                                                 const unsigned short* __restrict__ oin,
                                                 const float* __restrict__ g,
                                                 const float* __restrict__ b,
                                                 float* __restrict__ xout,
                                                 unsigned short* __restrict__ bfout) {
  const int lane = threadIdx.x & 63;
  const int wave = threadIdx.x >> 6;
  const size_t row  = (size_t)blockIdx.x * 4 + wave;
  const size_t base = row * 256 + lane * 4;
  float4 xv = *(const float4*)(xin + base);
  ushortx4 ou = *(const ushortx4*)(oin + base);
  const float x0 = xv.x + bf2f(ou.x), x1 = xv.y + bf2f(ou.y),
              x2 = xv.z + bf2f(ou.z), x3 = xv.w + bf2f(ou.w);
  float sum = x0 + x1 + x2 + x3;
  float ss  = x0 * x0 + x1 * x1 + x2 * x2 + x3 * x3;
#pragma unroll
  for (int m = 1; m <= 32; m <<= 1) {
    sum += __shfl_xor(sum, m);
    ss  += __shfl_xor(ss, m);
  }
  const float mu  = sum * (1.f / 256.f);
  const float var = ss * (1.f / 256.f) - mu * mu;
  const float rs  = rsqrtf(var + LN_EPS);
  float4 gv = *(const float4*)(g + lane * 4);
  float4 bv = *(const float4*)(b + lane * 4);
  const float y0 = (x0 - mu) * rs * gv.x + bv.x;
  const float y1 = (x1 - mu) * rs * gv.y + bv.y;
  const float y2 = (x2 - mu) * rs * gv.z + bv.z;
  const float y3 = (x3 - mu) * rs * gv.w + bv.w;
  *(float4*)(xout + base) = make_float4(y0, y1, y2, y3);
  if (WRITE_BF) {
    ushortx4 yo;
    yo.x = f2bf(y0); yo.y = f2bf(y1); yo.z = f2bf(y2); yo.w = f2bf(y3);
    *(ushortx4*)(bfout + base) = yo;
  }
}

// ---------------- launch ----------------
extern "C" void kernel_launch(void* const* d_in, const int* in_sizes, int n_in,
                              void* d_out, int out_size, void* d_ws, size_t ws_size,
                              hipStream_t stream) {
  const float* h_in      = (const float*)d_in[0];
  const float* mem_in    = (const float*)d_in[1];
  const int*   src_intra = (const int*)d_in[2];
  const int*   dst_intra = (const int*)d_in[3];
  const int*   etype     = (const int*)d_in[4];
  const int*   src_inter = (const int*)d_in[5];
  const int*   dst_inter = (const int*)d_in[6];
  const float* Wq0 = (const float*)d_in[7];
  const float* Wk0 = (const float*)d_in[8];
  const float* Wv0 = (const float*)d_in[9];
  const float* Wo0 = (const float*)d_in[10];
  const float* Wq1 = (const float*)d_in[11];
  const float* Wk1 = (const float*)d_in[12];
  const float* Wv1 = (const float*)d_in[13];
  const float* Wo1 = (const float*)d_in[14];
  const float* akE = (const float*)d_in[15];
  const float* ln0_g = (const float*)d_in[16];
  const float* ln0_b = (const float*)d_in[17];
  const float* ln1_g = (const float*)d_in[18];
  const float* ln1_b = (const float*)d_in[19];
  const float* ln2_g = (const float*)d_in[20];
  const float* ln2_b = (const float*)d_in[21];
  const float* Wf1 = (const float*)d_in[22];
  const float* bf1 = (const float*)d_in[23];
  const float* Wf2 = (const float*)d_in[24];
  const float* bf2 = (const float*)d_in[25];

  char* p = (char*)d_ws;
  auto alloc = [&](size_t bytes) {
    char* r = p;
    p += (bytes + 255) & ~(size_t)255;
    return r;
  };

  unsigned short* wqkv0t = (unsigned short*)alloc((size_t)768 * 256 * 2);
  unsigned short* wo0t   = (unsigned short*)alloc((size_t)256 * 256 * 2);
  unsigned short* wq1t   = (unsigned short*)alloc((size_t)256 * 256 * 2);
  unsigned short* wkv1t  = (unsigned short*)alloc((size_t)512 * 256 * 2);
  unsigned short* wo1t   = (unsigned short*)alloc((size_t)256 * 256 * 2);
  unsigned short* wf1t   = (unsigned short*)alloc((size_t)1024 * 256 * 2);
  unsigned short* wf2t   = (unsigned short*)alloc((size_t)256 * 1024 * 2);

  int* cnt0  = (int*)alloc((size_t)N_NODES * 4);
  int* rs0   = (int*)alloc((size_t)(N_NODES + 1) * 4);
  int* cur0  = (int*)alloc((size_t)N_NODES * 4);
  int* cnt1  = (int*)alloc((size_t)N_NODES * 4);
  int* rs1   = (int*)alloc((size_t)(N_NODES + 1) * 4);
  int* cur1  = (int*)alloc((size_t)N_NODES * 4);
  int* ssrc0 = (int*)alloc((size_t)E1_N * 4);
  int* set0  = (int*)alloc((size_t)E1_N * 4);
  int* ssrc1 = (int*)alloc((size_t)E2_N * 4);

  // buf1 [N,1024] capacity:
  //   phase1: qkv0 [N,768] + O0-out in tail [N,256]
  //   phase2: q1 [N,256] + kv1 [N,512] + O1-out in tail [N,256]
  //   phase3: ffn hidden [N,1024]
  unsigned short* buf1 = (unsigned short*)alloc((size_t)N_NODES * 1024 * 2);
  unsigned short* tail = buf1 + (size_t)N_NODES * 768;
  // buf2: h_bf -> attn0_out -> h1_bf -> attn1_out -> ffn2 out
  unsigned short* buf2 = (unsigned short*)alloc((size_t)N_NODES * 256 * 2);
  // buf3: mem_bf -> h2_bf
  unsigned short* buf3 = (unsigned short*)alloc((size_t)N_NODES * 256 * 2);

  float* hcur = (float*)d_out;  // fp32 residual chain lives in d_out

  const int TB = 256;
  const int g64k = 256;  // 65536/256

  // ---- phase 0: weights, casts, CSR ----
  transpose_w<<<dim3(8, 8), TB, 0, stream>>>(Wq0, wqkv0t, 256, 256);
  transpose_w<<<dim3(8, 8), TB, 0, stream>>>(Wk0, wqkv0t + 65536, 256, 256);
  transpose_w<<<dim3(8, 8), TB, 0, stream>>>(Wv0, wqkv0t + 131072, 256, 256);
  transpose_w<<<dim3(8, 8), TB, 0, stream>>>(Wo0, wo0t, 256, 256);
  transpose_w<<<dim3(8, 8), TB, 0, stream>>>(Wq1, wq1t, 256, 256);
  transpose_w<<<dim3(8, 8), TB, 0, stream>>>(Wk1, wkv1t, 256, 256);
  transpose_w<<<dim3(8, 8), TB, 0, stream>>>(Wv1, wkv1t + 65536, 256, 256);
  transpose_w<<<dim3(8, 8), TB, 0, stream>>>(Wo1, wo1t, 256, 256);
  transpose_w<<<dim3(32, 8), TB, 0, stream>>>(Wf1, wf1t, 256, 1024);
  transpose_w<<<dim3(8, 32), TB, 0, stream>>>(Wf2, wf2t, 1024, 256);

  f2bf_kernel<<<16384, TB, 0, stream>>>(h_in, buf2, N_NODES * 256 / 4);
  f2bf_kernel<<<16384, TB, 0, stream>>>(mem_in, buf3, N_NODES * 256 / 4);

  zero_kernel<<<g64k, TB, 0, stream>>>(cnt0, N_NODES);
  zero_kernel<<<g64k, TB, 0, stream>>>(cnt1, N_NODES);
  hist_kernel<<<E1_N / 256, TB, 0, stream>>>(dst_intra, cnt0, E1_N);
  hist_kernel<<<E2_N / 256, TB, 0, stream>>>(dst_inter, cnt1, E2_N);
  scan_kernel<<<1, 1024, 0, stream>>>(cnt0, rs0, cur0, E1_N);
  scan_kernel<<<1, 1024, 0, stream>>>(cnt1, rs1, cur1, E2_N);
  scatter_kernel<<<E1_N / 256, TB, 0, stream>>>(src_intra, dst_intra, etype, cur0, ssrc0, set0, E1_N);
  scatter_kernel<<<E2_N / 256, TB, 0, stream>>>(src_inter, dst_inter, nullptr, cur1, ssrc1, nullptr, E2_N);

  // ---- phase 1: intra attention ----
  gemm_bf16<false, false><<<dim3(512, 6), TB, 0, stream>>>(buf2, wqkv0t, nullptr, buf1, 256, 768);
  attn_kernel<true><<<16384, TB, 0, stream>>>(buf1, 768, buf1 + 256, buf1 + 512, 768,
                                              rs0, ssrc0, set0, akE, buf2);
  gemm_bf16<false, false><<<dim3(512, 2), TB, 0, stream>>>(buf2, wo0t, nullptr, tail, 256, 256);
  ln_kernel<true><<<16384, TB, 0, stream>>>(h_in, tail, ln0_g, ln0_b, hcur, buf2);

  // ---- phase 2: inter attention ----
  gemm_bf16<false, false><<<dim3(512, 2), TB, 0, stream>>>(buf2, wq1t, nullptr, buf1, 256, 256);
  unsigned short* kv1 = buf1 + (size_t)N_NODES * 256;
  gemm_bf16<false, false><<<dim3(512, 4), TB, 0, stream>>>(buf3, wkv1t, nullptr, kv1, 256, 512);
  attn_kernel<false><<<16384, TB, 0, stream>>>(buf1, 256, kv1, kv1 + 256, 512,
                                               rs1, ssrc1, nullptr, nullptr, buf2);
  gemm_bf16<false, false><<<dim3(512, 2), TB, 0, stream>>>(buf2, wo1t, nullptr, tail, 256, 256);
  ln_kernel<true><<<16384, TB, 0, stream>>>(hcur, tail, ln1_g, ln1_b, hcur, buf3);

  // ---- phase 3: FFN ----
  gemm_bf16<true, true><<<dim3(512, 8), TB, 0, stream>>>(buf3, wf1t, bf1, buf1, 256, 1024);
  gemm_bf16<true, false><<<dim3(512, 2), TB, 0, stream>>>(buf1, wf2t, bf2, buf2, 1024, 256);
  ln_kernel<false><<<16384, TB, 0, stream>>>(hcur, buf2, ln2_g, ln2_b, hcur, nullptr);
}

// Round 4
// 1059.327 us; speedup vs baseline: 1.0875x; 1.0601x over previous
//
#include <hip/hip_runtime.h>

// ---------------- constants ----------------
#define N_NODES 65536
#define D_MODEL 256
#define DFF     1024
#define E1_N    1048576
#define E2_N    524288
#define ATT_SCALE 0.17677669529663687f   // 1/sqrt(32)
#define LN_EPS  1e-5f

typedef __attribute__((ext_vector_type(8))) __bf16 bf16x8;
typedef __attribute__((ext_vector_type(4))) float  floatx4;
typedef __attribute__((ext_vector_type(4))) unsigned short ushortx4;
typedef __attribute__((ext_vector_type(8))) unsigned short ushortx8;

__device__ __forceinline__ float bf2f(unsigned short u) {
  return __uint_as_float(((unsigned)u) << 16);
}
__device__ __forceinline__ unsigned short f2bf(float f) {
  unsigned u = __float_as_uint(f);
  return (unsigned short)((u + 0x7FFFu + ((u >> 16) & 1u)) >> 16);
}

// async global->LDS, 16B per lane; LDS dst is wave-uniform base (+lane*16 by HW)
__device__ __forceinline__ void gld_lds16(const void* g, void* l) {
  __builtin_amdgcn_global_load_lds(
      (const __attribute__((address_space(1))) unsigned int*)g,
      (__attribute__((address_space(3))) unsigned int*)l, 16, 0, 0);
}

// ---------------- prep kernels ----------------
// batched: 8 square 256x256 fp32 -> bf16 transposes in one launch (z selects)
struct TW8 {
  const float* w[8];
  unsigned short* o[8];
};
__global__ __launch_bounds__(256) void transpose8(TW8 t) {
  __shared__ float tile[32][33];
  const int z = blockIdx.z;
  const float* W = t.w[z];
  unsigned short* Wt = t.o[z];
  const int tx = threadIdx.x & 31;
  const int ty = threadIdx.x >> 5;  // 0..7
  const int r0 = blockIdx.y * 32;
  const int c0 = blockIdx.x * 32;
#pragma unroll
  for (int p = 0; p < 4; ++p) {
    const int r = ty + p * 8;
    tile[r][tx] = W[(size_t)(r0 + r) * 256 + c0 + tx];
  }
  __syncthreads();
#pragma unroll
  for (int p = 0; p < 4; ++p) {
    const int r = ty + p * 8;
    Wt[(size_t)(c0 + r) * 256 + r0 + tx] = f2bf(tile[tx][r]);
  }
}

// generic single transpose: W [K][Nc] fp32 -> Wt [Nc][K] bf16
__global__ __launch_bounds__(256) void transpose_w(const float* __restrict__ W,
                                                   unsigned short* __restrict__ Wt,
                                                   int K, int Nc) {
  __shared__ float tile[32][33];
  const int tx = threadIdx.x & 31;
  const int ty = threadIdx.x >> 5;
  const int r0 = blockIdx.y * 32;
  const int c0 = blockIdx.x * 32;
#pragma unroll
  for (int p = 0; p < 4; ++p) {
    const int r = ty + p * 8;
    tile[r][tx] = W[(size_t)(r0 + r) * Nc + c0 + tx];
  }
  __syncthreads();
#pragma unroll
  for (int p = 0; p < 4; ++p) {
    const int r = ty + p * 8;
    Wt[(size_t)(c0 + r) * K + r0 + tx] = f2bf(tile[tx][r]);
  }
}

// both fp32->bf16 casts (h -> buf2, mem -> buf3) in one launch
__global__ __launch_bounds__(256) void f2bf2_kernel(const float* __restrict__ in0,
                                                    unsigned short* __restrict__ out0,
                                                    const float* __restrict__ in1,
                                                    unsigned short* __restrict__ out1,
                                                    int half) {
  int i = blockIdx.x * 256 + threadIdx.x;
  const float* in = (i < half) ? in0 : in1;
  unsigned short* out = (i < half) ? out0 : out1;
  int k = (i < half) ? i : i - half;
  float4 v = ((const float4*)in)[k];
  ushortx4 o;
  o.x = f2bf(v.x); o.y = f2bf(v.y); o.z = f2bf(v.z); o.w = f2bf(v.w);
  ((ushortx4*)out)[k] = o;
}

__global__ __launch_bounds__(256) void zero_kernel(int* __restrict__ p, int n) {
  int i = blockIdx.x * 256 + threadIdx.x;
  if (i < n) p[i] = 0;
}

// ---------------- CSR build (both graphs per launch) ----------------
__global__ __launch_bounds__(256) void hist2_kernel(const int* __restrict__ d0,
                                                    int* __restrict__ c0,
                                                    const int* __restrict__ d1,
                                                    int* __restrict__ c1) {
  int e = blockIdx.x * 256 + threadIdx.x;
  if (e < E1_N) atomicAdd(&c0[d0[e]], 1);
  if (e < E2_N) atomicAdd(&c1[d1[e]], 1);
}

// 2 blocks, 1024 threads each: block b scans graph b's counts
__global__ __launch_bounds__(1024) void scan2_kernel(int* __restrict__ cnt0,
                                                     int* __restrict__ rs0,
                                                     int* __restrict__ cur0,
                                                     int* __restrict__ cnt1,
                                                     int* __restrict__ rs1,
                                                     int* __restrict__ cur1) {
  int* cnt = blockIdx.x ? cnt1 : cnt0;
  int* row_start = blockIdx.x ? rs1 : rs0;
  int* cur = blockIdx.x ? cur1 : cur0;
  const int total = blockIdx.x ? E2_N : E1_N;
  __shared__ int lds[1024];
  const int tid = threadIdx.x;
  const int base = tid * 64;
  int s = 0;
  for (int i = 0; i < 64; ++i) s += cnt[base + i];
  lds[tid] = s;
  __syncthreads();
  int v = s;
  for (int off = 1; off < 1024; off <<= 1) {
    int add = (tid >= off) ? lds[tid - off] : 0;
    __syncthreads();
    v += add;
    lds[tid] = v;
    __syncthreads();
  }
  int run = v - s;
  for (int i = 0; i < 64; ++i) {
    int c = cnt[base + i];
    row_start[base + i] = run;
    cur[base + i] = run;
    run += c;
  }
  if (tid == 1023) row_start[N_NODES] = total;
}

// scatter both graphs; intra payload packed as int2{src, etype}
__global__ __launch_bounds__(256) void scatter2_kernel(const int* __restrict__ s0,
                                                       const int* __restrict__ d0,
                                                       const int* __restrict__ et,
                                                       int* __restrict__ cur0,
                                                       int2* __restrict__ out0,
                                                       const int* __restrict__ s1,
                                                       const int* __restrict__ d1,
                                                       int* __restrict__ cur1,
                                                       int* __restrict__ out1) {
  int e = blockIdx.x * 256 + threadIdx.x;
  if (e < E1_N) {
    int p = atomicAdd(&cur0[d0[e]], 1);
    out0[p] = make_int2(s0[e], et[e]);
  }
  if (e < E2_N) {
    int p = atomicAdd(&cur1[d1[e]], 1);
    out1[p] = s1[e];
  }
}

// ---------------- GEMM: C[M][N] = A[M][K] @ Bt[N][K]^T, bf16 in, bf16 out ----------------
// 128x128 tile / block of 256 threads (4 waves, 2x2 of 64x64), BK=32.
// grid: x = n-tile (fast-varying, shares A tile-row in L2), y = m-tile.
template <bool BIAS, bool RELU>
__global__ __launch_bounds__(256) void gemm_bf16(const unsigned short* __restrict__ A,
                                                 const unsigned short* __restrict__ Bt,
                                                 const float* __restrict__ bias,
                                                 unsigned short* __restrict__ C,
                                                 int K, int Ntot) {
  __shared__ __align__(16) unsigned short sA[128 * 32];
  __shared__ __align__(16) unsigned short sB[128 * 32];
  const int tid  = threadIdx.x;
  const int wave = tid >> 6;
  const int lane = tid & 63;
  const int m0 = blockIdx.y * 128;
  const int n0 = blockIdx.x * 128;

  floatx4 acc[4][4] = {};

  const int l4r = lane >> 2;        // 0..15: row within 16-row staging chunk
  const int l4c = (lane & 3) * 8;   // bf16 col offset within BK=32 (16B granule)
  const int fr = lane & 15;         // m/n within 16x16 tile
  const int fk = (lane >> 4) * 8;   // k offset of this lane-quad
  const int wy = (wave >> 1) * 64;  // wave's m offset
  const int wx = (wave & 1) * 64;   // wave's n offset

  for (int k0 = 0; k0 < K; k0 += 32) {
#pragma unroll
    for (int c = 0; c < 2; ++c) {
      const int row = wave * 32 + c * 16;
      gld_lds16(A  + ((size_t)(m0 + row + l4r) * K + k0 + l4c), &sA[row * 32]);
      gld_lds16(Bt + ((size_t)(n0 + row + l4r) * K + k0 + l4c), &sB[row * 32]);
    }
    __syncthreads();
    bf16x8 af[4], bfv[4];
#pragma unroll
    for (int i = 0; i < 4; ++i) af[i]  = *(const bf16x8*)&sA[(wy + i * 16 + fr) * 32 + fk];
#pragma unroll
    for (int j = 0; j < 4; ++j) bfv[j] = *(const bf16x8*)&sB[(wx + j * 16 + fr) * 32 + fk];
#pragma unroll
    for (int i = 0; i < 4; ++i)
#pragma unroll
      for (int j = 0; j < 4; ++j)
        acc[i][j] = __builtin_amdgcn_mfma_f32_16x16x32_bf16(af[i], bfv[j], acc[i][j], 0, 0, 0);
    __syncthreads();
  }

  // epilogue: D col(n) = lane&15, row(m) = (lane>>4)*4 + r
  const int coln = lane & 15;
  const int rowq = (lane >> 4) * 4;
#pragma unroll
  for (int j = 0; j < 4; ++j) {
    const int n = n0 + wx + j * 16 + coln;
    float bval = 0.f;
    if (BIAS) bval = bias[n];
#pragma unroll
    for (int i = 0; i < 4; ++i) {
      const int mbase = m0 + wy + i * 16 + rowq;
#pragma unroll
      for (int r = 0; r < 4; ++r) {
        float v = acc[i][j][r] + bval;
        if (RELU) v = fmaxf(v, 0.f);
        C[(size_t)(mbase + r) * Ntot + n] = f2bf(v);
      }
    }
  }
}

// ---------------- fused per-dst graph attention ----------------
// one wave per dst node, FOUR edges in flight per iteration:
// lane = edge-group(2b) x l(4b); lane covers 16 dims (two 16B loads); head = l>>1
template <bool HAS_REL>
__global__ __launch_bounds__(256) void attn_kernel(const unsigned short* __restrict__ qb, int qstride,
                                                   const unsigned short* __restrict__ kb,
                                                   const unsigned short* __restrict__ vb, int kvstride,
                                                   const int* __restrict__ row_start,
                                                   const int2* __restrict__ s_se,
                                                   const int* __restrict__ s_src,
                                                   const float* __restrict__ ak_embed,
                                                   unsigned short* __restrict__ outp) {
  const int lane = threadIdx.x & 63;
  const int wave = threadIdx.x >> 6;
  const int dst  = blockIdx.x * 4 + wave;
  const int eg   = lane >> 4;   // edge slot 0..3
  const int l    = lane & 15;   // 16 lanes per edge; head = l>>1
  const int doff = l * 16;      // dims [l*16, l*16+16)

  const unsigned short* qrow = qb + (size_t)dst * qstride + doff;
  ushortx8 qu0 = *(const ushortx8*)qrow;
  ushortx8 qu1 = *(const ushortx8*)(qrow + 8);
  float q[16];
#pragma unroll
  for (int d = 0; d < 8; ++d) {
    q[d]     = bf2f(qu0[d]) * ATT_SCALE;   // pre-scale: e = (k.q + ak.q)*SCALE
    q[d + 8] = bf2f(qu1[d]) * ATT_SCALE;
  }

  float a[16];
#pragma unroll
  for (int d = 0; d < 16; ++d) a[d] = 0.f;
  float lsum = 0.f;

  const int beg = row_start[dst], end = row_start[dst + 1];
  for (int j = beg; j < end; j += 4) {
    const int e = j + eg;
    const bool valid = e < end;
    const int ecl = valid ? e : (end - 1);
    int src, et = 0;
    if (HAS_REL) {
      int2 se = s_se[ecl];
      src = se.x; et = se.y;
    } else {
      src = s_src[ecl];
    }
    const unsigned short* kr = kb + (size_t)src * kvstride + doff;
    const unsigned short* vr = vb + (size_t)src * kvstride + doff;
    ushortx8 k0 = *(const ushortx8*)kr;
    ushortx8 k1 = *(const ushortx8*)(kr + 8);
    ushortx8 v0 = *(const ushortx8*)vr;
    ushortx8 v1 = *(const ushortx8*)(vr + 8);
    float part = 0.f;
#pragma unroll
    for (int d = 0; d < 8; ++d) part += bf2f(k0[d]) * q[d] + bf2f(k1[d]) * q[d + 8];
    if (HAS_REL) {
      const float* ak = ak_embed + (size_t)et * 32 + (l & 1) * 16;
      float4 a0 = *(const float4*)ak;
      float4 a1 = *(const float4*)(ak + 4);
      float4 a2 = *(const float4*)(ak + 8);
      float4 a3 = *(const float4*)(ak + 12);
      part += a0.x * q[0]  + a0.y * q[1]  + a0.z * q[2]  + a0.w * q[3]
            + a1.x * q[4]  + a1.y * q[5]  + a1.z * q[6]  + a1.w * q[7]
            + a2.x * q[8]  + a2.y * q[9]  + a2.z * q[10] + a2.w * q[11]
            + a3.x * q[12] + a3.y * q[13] + a3.z * q[14] + a3.w * q[15];
    }
    part += __shfl_xor(part, 1);  // pair-reduce: both lanes of head l>>1 hold score
    // e*SCALE ~ N(0,1): exp-safe without segment-max (softmax shift-invariant)
    const float pw = valid ? __expf(part) : 0.f;
    lsum += pw;
#pragma unroll
    for (int d = 0; d < 8; ++d) {
      a[d]     += pw * bf2f(v0[d]);
      a[d + 8] += pw * bf2f(v1[d]);
    }
  }
  // combine the four edge groups (same dims/head at same l)
  lsum += __shfl_xor(lsum, 16);
  lsum += __shfl_xor(lsum, 32);
#pragma unroll
  for (int d = 0; d < 16; ++d) {
    a[d] += __shfl_xor(a[d], 16);
    a[d] += __shfl_xor(a[d], 32);
  }
  const float inv = lsum > 0.f ? 1.f / lsum : 0.f;
  if (eg == 0) {
    ushortx8 o0, o1;
#pragma unroll
    for (int d = 0; d < 8; ++d) {
      o0[d] = f2bf(a[d] * inv);
      o1[d] = f2bf(a[d + 8] * inv);
    }
    unsigned short* orow = outp + (size_t)dst * 256 + doff;
    *(ushortx8*)orow = o0;
    *(ushortx8*)(orow + 8) = o1;
  }
}

// ---------------- residual + LayerNorm (wave per row, in-place safe) ----------------
template <bool WRITE_BF>
__global__ __launch_bounds__(256) void ln_kernel(const float* __restrict__ xin,
                                                 const unsigned short* __restrict__ oin,
                                                 const float* __restrict__ g,
                                                 const float* __restrict__ b,
                                                 float* __restrict__ xout,
                                                 unsigned short* __restrict__ bfout) {
  const int lane = threadIdx.x & 63;
  const int wave = threadIdx.x >> 6;
  const size_t row  = (size_t)blockIdx.x * 4 + wave;
  const size_t base = row * 256 + lane * 4;
  float4 xv = *(const float4*)(xin + base);
  ushortx4 ou = *(const ushortx4*)(oin + base);
  const float x0 = xv.x + bf2f(ou.x), x1 = xv.y + bf2f(ou.y),
              x2 = xv.z + bf2f(ou.z), x3 = xv.w + bf2f(ou.w);
  float sum = x0 + x1 + x2 + x3;
  float ss  = x0 * x0 + x1 * x1 + x2 * x2 + x3 * x3;
#pragma unroll
  for (int m = 1; m <= 32; m <<= 1) {
    sum += __shfl_xor(sum, m);
    ss  += __shfl_xor(ss, m);
  }
  const float mu  = sum * (1.f / 256.f);
  const float var = ss * (1.f / 256.f) - mu * mu;
  const float rs  = rsqrtf(var + LN_EPS);
  float4 gv = *(const float4*)(g + lane * 4);
  float4 bv = *(const float4*)(b + lane * 4);
  const float y0 = (x0 - mu) * rs * gv.x + bv.x;
  const float y1 = (x1 - mu) * rs * gv.y + bv.y;
  const float y2 = (x2 - mu) * rs * gv.z + bv.z;
  const float y3 = (x3 - mu) * rs * gv.w + bv.w;
  *(float4*)(xout + base) = make_float4(y0, y1, y2, y3);
  if (WRITE_BF) {
    ushortx4 yo;
    yo.x = f2bf(y0); yo.y = f2bf(y1); yo.z = f2bf(y2); yo.w = f2bf(y3);
    *(ushortx4*)(bfout + base) = yo;
  }
}

// ---------------- launch ----------------
extern "C" void kernel_launch(void* const* d_in, const int* in_sizes, int n_in,
                              void* d_out, int out_size, void* d_ws, size_t ws_size,
                              hipStream_t stream) {
  const float* h_in      = (const float*)d_in[0];
  const float* mem_in    = (const float*)d_in[1];
  const int*   src_intra = (const int*)d_in[2];
  const int*   dst_intra = (const int*)d_in[3];
  const int*   etype     = (const int*)d_in[4];
  const int*   src_inter = (const int*)d_in[5];
  const int*   dst_inter = (const int*)d_in[6];
  const float* Wq0 = (const float*)d_in[7];
  const float* Wk0 = (const float*)d_in[8];
  const float* Wv0 = (const float*)d_in[9];
  const float* Wo0 = (const float*)d_in[10];
  const float* Wq1 = (const float*)d_in[11];
  const float* Wk1 = (const float*)d_in[12];
  const float* Wv1 = (const float*)d_in[13];
  const float* Wo1 = (const float*)d_in[14];
  const float* akE = (const float*)d_in[15];
  const float* ln0_g = (const float*)d_in[16];
  const float* ln0_b = (const float*)d_in[17];
  const float* ln1_g = (const float*)d_in[18];
  const float* ln1_b = (const float*)d_in[19];
  const float* ln2_g = (const float*)d_in[20];
  const float* ln2_b = (const float*)d_in[21];
  const float* Wf1 = (const float*)d_in[22];
  const float* bf1 = (const float*)d_in[23];
  const float* Wf2 = (const float*)d_in[24];
  const float* bf2 = (const float*)d_in[25];

  char* p = (char*)d_ws;
  auto alloc = [&](size_t bytes) {
    char* r = p;
    p += (bytes + 255) & ~(size_t)255;
    return r;
  };

  unsigned short* wqkv0t = (unsigned short*)alloc((size_t)768 * 256 * 2);
  unsigned short* wo0t   = (unsigned short*)alloc((size_t)256 * 256 * 2);
  unsigned short* wq1t   = (unsigned short*)alloc((size_t)256 * 256 * 2);
  unsigned short* wkv1t  = (unsigned short*)alloc((size_t)512 * 256 * 2);
  unsigned short* wo1t   = (unsigned short*)alloc((size_t)256 * 256 * 2);
  unsigned short* wf1t   = (unsigned short*)alloc((size_t)1024 * 256 * 2);
  unsigned short* wf2t   = (unsigned short*)alloc((size_t)256 * 1024 * 2);

  int* cnt01 = (int*)alloc((size_t)2 * N_NODES * 4);  // cnt0 | cnt1 adjacent
  int* cnt0 = cnt01;
  int* cnt1 = cnt01 + N_NODES;
  int* rs0   = (int*)alloc((size_t)(N_NODES + 1) * 4);
  int* cur0  = (int*)alloc((size_t)N_NODES * 4);
  int* rs1   = (int*)alloc((size_t)(N_NODES + 1) * 4);
  int* cur1  = (int*)alloc((size_t)N_NODES * 4);
  int2* sse0 = (int2*)alloc((size_t)E1_N * 8);  // packed {src, etype}
  int* ssrc1 = (int*)alloc((size_t)E2_N * 4);

  // buf1 [N,1024] capacity:
  //   phase1: qkv0 [N,768] + O0-out in tail [N,256]
  //   phase2: q1 [N,256] + kv1 [N,512] + O1-out in tail [N,256]
  //   phase3: ffn hidden [N,1024]
  unsigned short* buf1 = (unsigned short*)alloc((size_t)N_NODES * 1024 * 2);
  unsigned short* tail = buf1 + (size_t)N_NODES * 768;
  // buf2: h_bf -> attn0_out -> h1_bf -> attn1_out -> ffn2 out
  unsigned short* buf2 = (unsigned short*)alloc((size_t)N_NODES * 256 * 2);
  // buf3: mem_bf -> h2_bf
  unsigned short* buf3 = (unsigned short*)alloc((size_t)N_NODES * 256 * 2);

  float* hcur = (float*)d_out;  // fp32 residual chain lives in d_out

  const int TB = 256;

  // ---- phase 0: weights, casts, CSR ----
  TW8 tw;
  tw.w[0] = Wq0; tw.o[0] = wqkv0t;
  tw.w[1] = Wk0; tw.o[1] = wqkv0t + 65536;
  tw.w[2] = Wv0; tw.o[2] = wqkv0t + 131072;
  tw.w[3] = Wo0; tw.o[3] = wo0t;
  tw.w[4] = Wq1; tw.o[4] = wq1t;
  tw.w[5] = Wk1; tw.o[5] = wkv1t;
  tw.w[6] = Wv1; tw.o[6] = wkv1t + 65536;
  tw.w[7] = Wo1; tw.o[7] = wo1t;
  transpose8<<<dim3(8, 8, 8), TB, 0, stream>>>(tw);
  transpose_w<<<dim3(32, 8), TB, 0, stream>>>(Wf1, wf1t, 256, 1024);
  transpose_w<<<dim3(8, 32), TB, 0, stream>>>(Wf2, wf2t, 1024, 256);

  f2bf2_kernel<<<32768, TB, 0, stream>>>(h_in, buf2, mem_in, buf3, N_NODES * 256 / 4);

  zero_kernel<<<512, TB, 0, stream>>>(cnt01, 2 * N_NODES);
  hist2_kernel<<<E1_N / 256, TB, 0, stream>>>(dst_intra, cnt0, dst_inter, cnt1);
  scan2_kernel<<<2, 1024, 0, stream>>>(cnt0, rs0, cur0, cnt1, rs1, cur1);
  scatter2_kernel<<<E1_N / 256, TB, 0, stream>>>(src_intra, dst_intra, etype, cur0, sse0,
                                                 src_inter, dst_inter, cur1, ssrc1);

  // ---- phase 1: intra attention ----
  gemm_bf16<false, false><<<dim3(6, 512), TB, 0, stream>>>(buf2, wqkv0t, nullptr, buf1, 256, 768);
  attn_kernel<true><<<16384, TB, 0, stream>>>(buf1, 768, buf1 + 256, buf1 + 512, 768,
                                              rs0, sse0, nullptr, akE, buf2);
  gemm_bf16<false, false><<<dim3(2, 512), TB, 0, stream>>>(buf2, wo0t, nullptr, tail, 256, 256);
  ln_kernel<true><<<16384, TB, 0, stream>>>(h_in, tail, ln0_g, ln0_b, hcur, buf2);

  // ---- phase 2: inter attention ----
  gemm_bf16<false, false><<<dim3(2, 512), TB, 0, stream>>>(buf2, wq1t, nullptr, buf1, 256, 256);
  unsigned short* kv1 = buf1 + (size_t)N_NODES * 256;
  gemm_bf16<false, false><<<dim3(4, 512), TB, 0, stream>>>(buf3, wkv1t, nullptr, kv1, 256, 512);
  attn_kernel<false><<<16384, TB, 0, stream>>>(buf1, 256, kv1, kv1 + 256, 512,
                                               rs1, nullptr, ssrc1, nullptr, buf2);
  gemm_bf16<false, false><<<dim3(2, 512), TB, 0, stream>>>(buf2, wo1t, nullptr, tail, 256, 256);
  ln_kernel<true><<<16384, TB, 0, stream>>>(hcur, tail, ln1_g, ln1_b, hcur, buf3);

  // ---- phase 3: FFN ----
  gemm_bf16<true, true><<<dim3(8, 512), TB, 0, stream>>>(buf3, wf1t, bf1, buf1, 256, 1024);
  gemm_bf16<true, false><<<dim3(2, 512), TB, 0, stream>>>(buf1, wf2t, bf2, buf2, 1024, 256);
  ln_kernel<false><<<16384, TB, 0, stream>>>(hcur, buf2, ln2_g, ln2_b, hcur, nullptr);
}